// Round 7
// baseline (94.277 us; speedup 1.0000x reference)
//
#include <hip/hip_runtime.h>

// Problem constants (fixed by setup_inputs)
#define BB    4
#define TT    300
#define NN    200
#define NINN  100
#define KK    10
#define DECAY 0.8f
#define THR   0.6f
#define DAMP  0.3f

#define LCH   20
#define NCHK  (TT / LCH)      // 15
#define WARM  48              // 0.8^48*5 ~ 1e-4 << tol

// ws layout (floats). zfilt dropped (dw_out uses z·gbar adjoint identity).
#define XBAR_OFF  0
#define ZBAR_OFF  (BB*TT*NINN)                  // 120000
#define CBUF_OFF  (ZBAR_OFF + BB*TT*NN)         // 360000
#define PART_OFF  (CBUF_OFF + BB*TT*NN)         // 600000 (12*2000 dw_out partials)

// Fused kernel block ranges (all block-uniform)
#define NB_A 24                         // xbar scan: 6000 threads
#define NB_B 47                         // zbar scan: 12000 threads
#define NB_C 240                        // c: 240 blocks x 5 bt x 50 jq
#define CB_BASE  (NB_A + NB_B)          // 71
#define DB_BASE  (CB_BASE + NB_C)       // 311
#define NB_D 12                         // dw_out partials: (b, t-third)
#define NBLK (DB_BASE + NB_D)           // 323

// ---------------------------------------------------------------------------
// Kernel 1 (fused): xbar scan || zbar scan || c-computation (gbar in LDS)
// || dw_out partials via identity sum_t e1*E(z) == sum_t R(e1)*z.
// No cross-block deps; no atomics. Region D gbar is WAVE-PARALLEL (1000
// independent 48-term windows) — R6's 10-thread serial chain was the long
// pole (+8us).
// ---------------------------------------------------------------------------
__global__ void fused_kernel(const float* __restrict__ v,
                             const float* __restrict__ z,
                             const float* __restrict__ x,
                             const float* __restrict__ error1,
                             const float* __restrict__ error2,
                             const float* __restrict__ w_out,
                             float* __restrict__ ws,
                             float* __restrict__ out) {
    __shared__ float smem[100 * KK];    // 4 KB scratch (regions C, D)
    int bid = blockIdx.x;
    int tid = threadIdx.x;
    float* xbar = ws + XBAR_OFF;
    float* zbar = ws + ZBAR_OFF;
    float* cbuf = ws + CBUF_OFF;
    float* part = ws + PART_OFF;

    if (bid < NB_A) {
        // ---- region A: xbar = exp_convolve(x) ----
        int u = bid * 256 + tid;
        if (u < BB * NCHK * NINN) {          // 6000
            int i = u % NINN, r = u / NINN;
            int chunk = r % NCHK, b = r / NCHK;
            int t0 = chunk * LCH;
            const float* src = x + (size_t)b * TT * NINN + i;
            float acc = 0.f;
            #pragma unroll
            for (int d = WARM; d >= 1; --d) {
                int t = t0 - d;
                int tc = t < 0 ? 0 : t;
                float val = src[tc * NINN];
                acc = DECAY * acc + (t < 0 ? 0.f : val);
            }
            float vals[LCH];
            #pragma unroll
            for (int tt = 0; tt < LCH; ++tt) vals[tt] = src[(t0 + tt) * NINN];
            #pragma unroll
            for (int tt = 0; tt < LCH; ++tt) { acc = DECAY * acc + vals[tt]; vals[tt] = acc; }
            float* dst = xbar + (size_t)b * TT * NINN + i;
            #pragma unroll
            for (int tt = 0; tt < LCH; ++tt) dst[(t0 + tt) * NINN] = vals[tt];
        }
    } else if (bid < CB_BASE) {
        // ---- region B: zbar[t] = exp_convolve(z)[t-1] ----
        int u = (bid - NB_A) * 256 + tid;
        if (u < BB * NCHK * NN) {            // 12000
            int j = u % NN, r = u / NN;
            int chunk = r % NCHK, b = r / NCHK;
            int t0 = chunk * LCH;
            const float* src = z + (size_t)b * TT * NN + j;
            float acc = 0.f;
            #pragma unroll
            for (int d = WARM; d >= 1; --d) {
                int t = t0 - d;
                int tc = t < 0 ? 0 : t;
                float val = src[tc * NN];
                acc = DECAY * acc + (t < 0 ? 0.f : val);
            }
            float zv[LCH], pre[LCH];
            #pragma unroll
            for (int tt = 0; tt < LCH; ++tt) zv[tt] = src[(t0 + tt) * NN];
            #pragma unroll
            for (int tt = 0; tt < LCH; ++tt) {
                pre[tt] = acc;                  // zbar[t] = zfilt[t-1]
                acc = DECAY * acc + zv[tt];
            }
            float* dzb = zbar + (size_t)b * TT * NN + j;
            #pragma unroll
            for (int tt = 0; tt < LCH; ++tt) dzb[(t0 + tt) * NN] = pre[tt];
        }
    } else if (bid < DB_BASE) {
        // ---- region C: c[bt,j] for 5 consecutive bt; gbar in LDS ----
        int cb = bid - CB_BASE;
        int bt0 = cb * 5;
        int b = bt0 / TT;
        int t0 = bt0 - b * TT;
        if (tid < 5 * KK) {
            int btl = tid / KK, k = tid - btl * KK;
            int t = t0 + btl;
            const float* src = error1 + (size_t)b * TT * KK + k;
            float G = 0.f;
            #pragma unroll
            for (int d = WARM - 1; d >= 0; --d) {
                int s = t + d;
                int sc = s > TT - 1 ? TT - 1 : s;
                float val = src[sc * KK];
                G = DECAY * G + (s > TT - 1 ? 0.f : val);
            }
            smem[btl * KK + k] = G;
        }
        __syncthreads();
        if (tid < 250) {
            int jq = tid % 50, btl = tid / 50;
            int t = t0 + btl;
            int bt = bt0 + btl;
            int j0 = jq * 4;

            float g[KK];
            #pragma unroll
            for (int k = 0; k < KK; ++k) g[k] = smem[btl * KK + k];

            float Ld[4];
            #pragma unroll
            for (int a = 0; a < 4; ++a) {
                const float* wr = w_out + (j0 + a) * KK;
                float acc = 0.f;
                #pragma unroll
                for (int k = 0; k < KK; ++k) acc += g[k] * wr[k];
                Ld[a] = acc;
            }

            float4 e2v = *(const float4*)(error2 + j0);
            float co[4] = {0.25f * e2v.x, 0.25f * e2v.y, 0.25f * e2v.z, 0.25f * e2v.w};

            bool refr[4] = {false, false, false, false};
            #pragma unroll
            for (int d = 1; d <= 4; ++d) {
                int s = t - d;
                int sc = s < 0 ? 0 : s;
                float4 zv = *(const float4*)(z + ((size_t)b * TT + sc) * NN + j0);
                if (s >= 0) {
                    if (zv.x > 0.f) refr[0] = true;
                    if (zv.y > 0.f) refr[1] = true;
                    if (zv.z > 0.f) refr[2] = true;
                    if (zv.w > 0.f) refr[3] = true;
                }
            }

            float4 vv = *(const float4*)(v + (size_t)bt * NN + j0);
            float vm[4] = {vv.x, vv.y, vv.z, vv.w};
            float cm[4];
            #pragma unroll
            for (int a = 0; a < 4; ++a) {
                float vs = (vm[a] - THR) / THR;
                float psi = (DAMP / THR) * fmaxf(1.f - fabsf(vs), 0.f);
                cm[a] = (refr[a] ? 0.f : psi) * (Ld[a] + co[a]);
            }
            *(float4*)(cbuf + (size_t)bt * NN + j0) = make_float4(cm[0], cm[1], cm[2], cm[3]);
        }
    } else {
        // ---- region D: dw_out partials, block s: b=s/3, t in [(s%3)*100,+100) ----
        // Phase 1: gbar[tl,k] for tl in [0,100): 1000 independent 48-term
        // windows spread over all 256 threads (4 items each) — parallel,
        // ILP-friendly, no serial long pole.
        int s = bid - DB_BASE;               // 0..11
        int b = s / 3;
        int t0 = (s % 3) * 100;
        const float* e1b = error1 + (size_t)b * TT * KK;
        #pragma unroll
        for (int r = 0; r < 4; ++r) {
            int item = tid + 256 * r;
            if (item < 100 * KK) {
                int tl = item / KK, k = item - tl * KK;
                int t = t0 + tl;
                float G = 0.f;
                #pragma unroll
                for (int d = WARM - 1; d >= 0; --d) {
                    int ss = t + d;
                    int sc = ss > TT - 1 ? TT - 1 : ss;
                    float val = e1b[sc * KK + k];
                    G = DECAY * G + (ss > TT - 1 ? 0.f : val);
                }
                smem[tl * KK + k] = G;
            }
        }
        __syncthreads();
        if (tid < NN) {
            const float* zp = z + ((size_t)b * TT + t0) * NN + tid;
            float acc[KK];
            #pragma unroll
            for (int k = 0; k < KK; ++k) acc[k] = 0.f;
            #pragma unroll 4
            for (int tt = 0; tt < 100; ++tt) {
                float zv = zp[tt * NN];
                #pragma unroll
                for (int k = 0; k < KK; ++k) acc[k] += zv * smem[tt * KK + k];
            }
            float* pd = part + s * (NN * KK) + tid * KK;
            #pragma unroll
            for (int k = 0; k < KK; ++k) pd[k] = acc[k];
        }
    }
}

// ---------------------------------------------------------------------------
// Kernel 2: blocked contraction (direct stores, no atomics).
//   Blocks 0..299: output tile 4p x 64j; 16 s-groups x 75 iters; LDS reduce.
//   Blocks 300..307: dw_out = sum of 12 partials.
// ---------------------------------------------------------------------------
#define SKB 16
#define KC3 (BB * TT / SKB)    // 75
#define PT  4
#define JT  64

__global__ void out_kernel(const float* __restrict__ ws,
                           float* __restrict__ out) {
    __shared__ float red[SKB * PT * JT];   // 16 KB
    int bid = blockIdx.x;
    int tid = threadIdx.x;
    const float* xbar = ws + XBAR_OFF;
    const float* zbar = ws + ZBAR_OFF;
    const float* cbuf = ws + CBUF_OFF;
    const float* part = ws + PART_OFF;

    if (bid < 300) {
        int pt = bid >> 2;                 // 0..74
        int jt = bid & 3;                  // 0..3
        int p0 = pt * PT;
        int j0 = jt * JT;
        int W = NN - j0; if (W > JT) W = JT;     // 64,64,64,8
        int jq = tid & 15;
        int s  = tid >> 4;

        if (jq * 4 < W) {
            bool isrec = (p0 >= NINN);
            const float* A = isrec ? (zbar + (p0 - NINN)) : (xbar + p0);
            int lda = isrec ? NN : NINN;
            const float* C = cbuf + j0 + jq * 4;
            int bt0 = s * KC3;
            float acc[4][4];
            #pragma unroll
            for (int a = 0; a < 4; ++a)
                #pragma unroll
                for (int c = 0; c < 4; ++c) acc[a][c] = 0.f;
            #pragma unroll 5
            for (int rr = 0; rr < KC3; ++rr) {
                int bt = bt0 + rr;
                float4 av = *(const float4*)(A + (size_t)bt * lda);
                float4 cv = *(const float4*)(C + (size_t)bt * NN);
                float am[4] = {av.x, av.y, av.z, av.w};
                float cm[4] = {cv.x, cv.y, cv.z, cv.w};
                #pragma unroll
                for (int a = 0; a < 4; ++a)
                    #pragma unroll
                    for (int c = 0; c < 4; ++c) acc[a][c] += am[a] * cm[c];
            }
            float* dst = red + s * (PT * JT) + jq * 4;
            #pragma unroll
            for (int a = 0; a < 4; ++a)
                *(float4*)(dst + a * JT) =
                    make_float4(acc[a][0], acc[a][1], acc[a][2], acc[a][3]);
        }
        __syncthreads();

        int o = tid;                       // p_local*64 + j_local
        int pl = o >> 6, jl = o & 63;
        if (jl < W) {
            float sum = 0.f;
            #pragma unroll
            for (int s2 = 0; s2 < SKB; ++s2) sum += red[s2 * (PT * JT) + o];
            int row = p0 + pl;
            int j = j0 + jl;
            if (row < NINN) {
                out[row * NN + j] = sum;
            } else {
                int i = row - NINN;
                out[NINN * NN + i * NN + j] = (i == j) ? 0.f : sum;
            }
        }
    } else {
        // dw_out tail: sum the 12 partials
        int u = (bid - 300) * 256 + tid;
        if (u < NN * KK) {
            float sum = 0.f;
            #pragma unroll
            for (int p = 0; p < 12; ++p) sum += part[p * (NN * KK) + u];
            out[NINN * NN + NN * NN + u] = sum;
        }
    }
}

extern "C" void kernel_launch(void* const* d_in, const int* in_sizes, int n_in,
                              void* d_out, int out_size, void* d_ws, size_t ws_size,
                              hipStream_t stream) {
    const float* v  = (const float*)d_in[0];
    const float* z  = (const float*)d_in[1];
    const float* x  = (const float*)d_in[2];
    const float* e1 = (const float*)d_in[3];
    const float* e2 = (const float*)d_in[4];
    const float* wo = (const float*)d_in[5];
    float* out = (float*)d_out;
    float* ws  = (float*)d_ws;

    fused_kernel<<<NBLK, 256, 0, stream>>>(v, z, x, e1, e2, wo, ws, out);

    out_kernel<<<308, 256, 0, stream>>>(ws, out);
}

// Round 8
// 84.671 us; speedup vs baseline: 1.1134x; 1.1134x over previous
//
#include <hip/hip_runtime.h>

// Problem constants (fixed by setup_inputs)
#define BB    4
#define TT    300
#define NN    200
#define NINN  100
#define KK    10
#define DECAY 0.8f
#define THR   0.6f
#define DAMP  0.3f

// R3-proven structure (85.56 us measured). Journal:
//  - dur_us includes ~84us of harness re-poison fills (2 x 42us, 256 MiB each);
//    controllable kernel time here is ~1.6-2us. R5 coop-launch: 104+84=188 (x).
//  - R4 split-K atomics: +2us (x). R6/R7 dw_out-identity region D: +8us
//    (cold-z latency pole) (x). This two-launch layout is the best measured.
#define LCH   20
#define NCHK  (TT / LCH)      // 15
#define WARM  48              // 0.8^48*5 ~ 1e-4 << 0.115 threshold

// ws layout (floats)
#define XBAR_OFF  0
#define ZFILT_OFF (BB*TT*NINN)                  // 120000
#define ZBAR_OFF  (ZFILT_OFF + BB*TT*NN)        // 360000
#define CBUF_OFF  (ZBAR_OFF  + BB*TT*NN)        // 600000

// Fused kernel block ranges (all conditions block-uniform)
#define NB_A 24                         // xbar scan: 6000 threads
#define NB_B 47                         // zfilt/zbar: 12000 threads
#define NB_C 240                        // c: 240 blocks x 5 bt x 50 jq
#define CB_BASE  (NB_A + NB_B)          // 71
#define ZB_BASE  (CB_BASE + NB_C)       // 311
#define NB_TOTAL (ZB_BASE + 2)          // 313 (last 2 blocks zero dw_out)

// ---------------------------------------------------------------------------
// Kernel 1 (fused): forward scans (xbar, zfilt/zbar)  ||  c-computation with
// per-block LDS gbar recompute  ||  zero dw_out region. No cross-block deps.
// ---------------------------------------------------------------------------
__global__ void fused_kernel(const float* __restrict__ v,
                             const float* __restrict__ z,
                             const float* __restrict__ x,
                             const float* __restrict__ error1,
                             const float* __restrict__ error2,
                             const float* __restrict__ w_out,
                             float* __restrict__ ws,
                             float* __restrict__ out) {
    int bid = blockIdx.x;
    int tid = threadIdx.x;
    float* xbar  = ws + XBAR_OFF;
    float* zfilt = ws + ZFILT_OFF;
    float* zbar  = ws + ZBAR_OFF;
    float* cbuf  = ws + CBUF_OFF;

    if (bid < NB_A) {
        // ---- region A: xbar = exp_convolve(x) ----
        int u = bid * 256 + tid;
        if (u < BB * NCHK * NINN) {          // 6000
            int i = u % NINN, r = u / NINN;
            int chunk = r % NCHK, b = r / NCHK;
            int t0 = chunk * LCH;
            const float* src = x + (size_t)b * TT * NINN + i;
            float acc = 0.f;
            #pragma unroll
            for (int d = WARM; d >= 1; --d) {
                int t = t0 - d;
                int tc = t < 0 ? 0 : t;
                float val = src[tc * NINN];
                acc = DECAY * acc + (t < 0 ? 0.f : val);
            }
            float vals[LCH];
            #pragma unroll
            for (int tt = 0; tt < LCH; ++tt) vals[tt] = src[(t0 + tt) * NINN];
            #pragma unroll
            for (int tt = 0; tt < LCH; ++tt) { acc = DECAY * acc + vals[tt]; vals[tt] = acc; }
            float* dst = xbar + (size_t)b * TT * NINN + i;
            #pragma unroll
            for (int tt = 0; tt < LCH; ++tt) dst[(t0 + tt) * NINN] = vals[tt];
        }
    } else if (bid < CB_BASE) {
        // ---- region B: zfilt = exp_convolve(z), zbar = zfilt shifted ----
        int u = (bid - NB_A) * 256 + tid;
        if (u < BB * NCHK * NN) {            // 12000
            int j = u % NN, r = u / NN;
            int chunk = r % NCHK, b = r / NCHK;
            int t0 = chunk * LCH;
            const float* src = z + (size_t)b * TT * NN + j;
            float acc = 0.f;
            #pragma unroll
            for (int d = WARM; d >= 1; --d) {
                int t = t0 - d;
                int tc = t < 0 ? 0 : t;
                float val = src[tc * NN];
                acc = DECAY * acc + (t < 0 ? 0.f : val);
            }
            float zv[LCH], pre[LCH];
            #pragma unroll
            for (int tt = 0; tt < LCH; ++tt) zv[tt] = src[(t0 + tt) * NN];
            #pragma unroll
            for (int tt = 0; tt < LCH; ++tt) {
                pre[tt] = acc;                  // zbar[t] = zfilt[t-1]
                acc = DECAY * acc + zv[tt];
                zv[tt] = acc;                   // zfilt[t]
            }
            float* dzb = zbar  + (size_t)b * TT * NN + j;
            float* dzf = zfilt + (size_t)b * TT * NN + j;
            #pragma unroll
            for (int tt = 0; tt < LCH; ++tt) dzb[(t0 + tt) * NN] = pre[tt];
            #pragma unroll
            for (int tt = 0; tt < LCH; ++tt) dzf[(t0 + tt) * NN] = zv[tt];
        }
    } else if (bid < ZB_BASE) {
        // ---- region C: c[bt,j] for 5 consecutive bt (never straddles b) ----
        __shared__ float gl[5][KK];
        int cb = bid - CB_BASE;
        int bt0 = cb * 5;
        int b = bt0 / TT;
        int t0 = bt0 - b * TT;
        if (tid < 5 * KK) {
            // gbar[t,k] = sum_{d=0..WARM-1} 0.8^d * e1[t+d,k]  (truncated)
            int btl = tid / KK, k = tid - btl * KK;
            int t = t0 + btl;
            const float* src = error1 + (size_t)b * TT * KK + k;
            float G = 0.f;
            #pragma unroll
            for (int d = WARM - 1; d >= 0; --d) {
                int s = t + d;
                int sc = s > TT - 1 ? TT - 1 : s;
                float val = src[sc * KK];
                G = DECAY * G + (s > TT - 1 ? 0.f : val);
            }
            gl[btl][k] = G;
        }
        __syncthreads();
        if (tid < 250) {
            int jq = tid % 50, btl = tid / 50;
            int t = t0 + btl;
            int bt = bt0 + btl;
            int j0 = jq * 4;

            float g[KK];
            #pragma unroll
            for (int k = 0; k < KK; ++k) g[k] = gl[btl][k];

            float Ld[4];
            #pragma unroll
            for (int a = 0; a < 4; ++a) {
                const float* wr = w_out + (j0 + a) * KK;
                float acc = 0.f;
                #pragma unroll
                for (int k = 0; k < KK; ++k) acc += g[k] * wr[k];
                Ld[a] = acc;
            }

            float4 e2v = *(const float4*)(error2 + j0);
            float co[4] = {0.25f * e2v.x, 0.25f * e2v.y, 0.25f * e2v.z, 0.25f * e2v.w};

            bool refr[4] = {false, false, false, false};
            #pragma unroll
            for (int d = 1; d <= 4; ++d) {
                int s = t - d;
                int sc = s < 0 ? 0 : s;
                float4 zv = *(const float4*)(z + ((size_t)b * TT + sc) * NN + j0);
                if (s >= 0) {
                    if (zv.x > 0.f) refr[0] = true;
                    if (zv.y > 0.f) refr[1] = true;
                    if (zv.z > 0.f) refr[2] = true;
                    if (zv.w > 0.f) refr[3] = true;
                }
            }

            float4 vv = *(const float4*)(v + (size_t)bt * NN + j0);
            float vm[4] = {vv.x, vv.y, vv.z, vv.w};
            float cm[4];
            #pragma unroll
            for (int a = 0; a < 4; ++a) {
                float vs = (vm[a] - THR) / THR;
                float psi = (DAMP / THR) * fmaxf(1.f - fabsf(vs), 0.f);
                cm[a] = (refr[a] ? 0.f : psi) * (Ld[a] + co[a]);
            }
            *(float4*)(cbuf + (size_t)bt * NN + j0) = make_float4(cm[0], cm[1], cm[2], cm[3]);
        }
    } else {
        // ---- zero dw_out region (2000 floats) for K2's atomic tail ----
        int u = (bid - ZB_BASE) * 256 + tid;
        if (u < 500)
            ((float4*)(out + NINN * NN + NN * NN))[u] = make_float4(0.f, 0.f, 0.f, 0.f);
    }
}

// ---------------------------------------------------------------------------
// Kernel 2: atomic-free blocked contraction.
//   Blocks 0..299: output tile 4p x 64j; 16 K-groups x 16 jq; LDS reduce;
//   coalesced direct store (rec diagonal stored as 0).
//   Blocks 300..346: dw_out, split-K=6 atomics into zeroed region.
// ---------------------------------------------------------------------------
#define SKB 16
#define KC3 (BB * TT / SKB)    // 75
#define PT  4
#define JT  64

__global__ void out_kernel(const float* __restrict__ error1,
                           const float* __restrict__ ws,
                           float* __restrict__ out) {
    __shared__ float red[SKB * PT * JT];   // 16 KB
    int bid = blockIdx.x;
    int tid = threadIdx.x;
    const float* xbar  = ws + XBAR_OFF;
    const float* zfilt = ws + ZFILT_OFF;
    const float* zbar  = ws + ZBAR_OFF;
    const float* cbuf  = ws + CBUF_OFF;

    if (bid < 300) {
        int pt = bid >> 2;                 // 0..74
        int jt = bid & 3;                  // 0..3
        int p0 = pt * PT;
        int j0 = jt * JT;
        int W = NN - j0; if (W > JT) W = JT;     // 64,64,64,8
        int jq = tid & 15;
        int s  = tid >> 4;

        if (jq * 4 < W) {
            bool isrec = (p0 >= NINN);
            const float* A = isrec ? (zbar + (p0 - NINN)) : (xbar + p0);
            int lda = isrec ? NN : NINN;
            const float* C = cbuf + j0 + jq * 4;
            int bt0 = s * KC3;
            float acc[4][4];
            #pragma unroll
            for (int a = 0; a < 4; ++a)
                #pragma unroll
                for (int c = 0; c < 4; ++c) acc[a][c] = 0.f;
            #pragma unroll 5
            for (int rr = 0; rr < KC3; ++rr) {
                int bt = bt0 + rr;
                float4 av = *(const float4*)(A + (size_t)bt * lda);
                float4 cv = *(const float4*)(C + (size_t)bt * NN);
                float am[4] = {av.x, av.y, av.z, av.w};
                float cm[4] = {cv.x, cv.y, cv.z, cv.w};
                #pragma unroll
                for (int a = 0; a < 4; ++a)
                    #pragma unroll
                    for (int c = 0; c < 4; ++c) acc[a][c] += am[a] * cm[c];
            }
            float* dst = red + s * (PT * JT) + jq * 4;
            #pragma unroll
            for (int a = 0; a < 4; ++a)
                *(float4*)(dst + a * JT) =
                    make_float4(acc[a][0], acc[a][1], acc[a][2], acc[a][3]);
        }
        __syncthreads();

        int o = tid;                       // p_local*64 + j_local
        int pl = o >> 6, jl = o & 63;
        if (jl < W) {
            float sum = 0.f;
            #pragma unroll
            for (int s2 = 0; s2 < SKB; ++s2) sum += red[s2 * (PT * JT) + o];
            int row = p0 + pl;
            int j = j0 + jl;
            if (row < NINN) {
                out[row * NN + j] = sum;
            } else {
                int i = row - NINN;
                out[NINN * NN + i * NN + j] = (i == j) ? 0.f : sum;
            }
        }
    } else {
        int u = (bid - 300) * 256 + tid;
        if (u < 6 * NN * KK) {
            int jk = u % (NN * KK);
            int s = u / (NN * KK);         // 0..5
            int j = jk % NN;               // lanes -> coalesced zfilt
            int k = jk / NN;
            int bt0 = s * 200;
            float acc = 0.f;
            #pragma unroll 8
            for (int rr = 0; rr < 200; ++rr) {
                int bt = bt0 + rr;
                acc += zfilt[bt * NN + j] * error1[bt * KK + k];
            }
            atomicAdd(out + NINN * NN + NN * NN + j * KK + k, acc);
        }
    }
}

extern "C" void kernel_launch(void* const* d_in, const int* in_sizes, int n_in,
                              void* d_out, int out_size, void* d_ws, size_t ws_size,
                              hipStream_t stream) {
    const float* v  = (const float*)d_in[0];
    const float* z  = (const float*)d_in[1];
    const float* x  = (const float*)d_in[2];
    const float* e1 = (const float*)d_in[3];
    const float* e2 = (const float*)d_in[4];
    const float* wo = (const float*)d_in[5];
    float* out = (float*)d_out;
    float* ws  = (float*)d_ws;

    fused_kernel<<<NB_TOTAL, 256, 0, stream>>>(z ? v : v, z, x, e1, e2, wo, ws, out);

    out_kernel<<<347, 256, 0, stream>>>(e1, ws, out);
}